// Round 3
// baseline (592.593 us; speedup 1.0000x reference)
//
#include <hip/hip_runtime.h>
#include <hip/hip_cooperative_groups.h>

namespace cg = cooperative_groups;

#define LN_EPS 1e-5f

constexpr int GRID_BLOCKS = 512;   // 2 blocks/CU on 256 CUs — cooperative-resident
constexpr int SMEM_FLOATS = 10368; // >= stage-1 requirement (10080 floats)

struct Params {
    const float* x;
    const float *w1,*b1,*g1,*be1;
    const float *w2,*b2,*g2,*be2;
    const float *w3,*b3,*g3,*be3;
    const float *w4,*b4,*g4,*be4;
    const float *w5,*b5,*g5,*be5;
    const float *w6,*b6,*g6,*be6;
    const float *fcw,*fcb;
    float* out;
    float* ws;
};

// ---------------------------------------------------------------------------
// One LC stage: [LN(prev stats) + optional 2x2 maxpool] -> locally-connected
// conv + bias + ReLU -> raw output + per-sample (sum,sumsq) atomics.
// Unit = (TILE x TILE tile) x (S samples); units spread over the whole grid.
// ---------------------------------------------------------------------------
template<int RIN, bool POOL, bool FIRST, int K, int TILE, int S>
__device__ void lc_stage_dev(float* sm,
                             const float* __restrict__ in,
                             const float* __restrict__ pstats,
                             const float* __restrict__ gamma,
                             const float* __restrict__ beta,
                             const float* __restrict__ w,
                             const float* __restrict__ bias,
                             float* __restrict__ out,
                             float* __restrict__ stats)
{
    constexpr int CIN  = POOL ? RIN/2 : RIN;
    constexpr int ROUT = CIN;
    constexpr int PAD  = (K-1)/2;
    constexpr int RT   = TILE + K - 1;
    constexpr int PP   = RT*RT + 1;          // odd stride -> conflict-light LDS
    constexpr int NBLK = ROUT / TILE;
    constexpr int WCNT = TILE*TILE*K*K;
    constexpr int SG   = 64 / S;
    constexpr int PG   = 256 / S;
    constexpr int OPT  = (TILE*TILE) / PG;
    constexpr int NUNIT= NBLK*NBLK*SG;
    constexpr float INV_NPREV = 1.0f / (float)(RIN*RIN);
    static_assert(PG*OPT == TILE*TILE, "position mapping must cover tile");

    float* s_in = sm;                 // S*PP
    float* s_w  = sm + S*PP;          // WCNT
    float* s_b  = s_w + WCNT;         // TILE*TILE
    float* s_mr = s_b + TILE*TILE;    // 2*S  (mean, rstd)
    float* s_red= s_mr + 2*S;         // 512

    const int tid = threadIdx.x;

    for (int unit = blockIdx.x; unit < NUNIT; unit += gridDim.x) {
        const int bt = unit % (NBLK*NBLK);
        const int sg = unit / (NBLK*NBLK);
        const int i0 = (bt / NBLK) * TILE;
        const int j0 = (bt % NBLK) * TILE;
        const int S0 = sg * S;

        if constexpr (!FIRST) {
            if (tid < S) {
                float mu  = pstats[S0 + tid] * INV_NPREV;
                float msq = pstats[64 + S0 + tid] * INV_NPREV;
                s_mr[tid]     = mu;
                s_mr[S + tid] = rsqrtf(msq - mu*mu + LN_EPS);
            }
        }
        for (int idx = tid; idx < WCNT; idx += 256) {
            int pi = idx / (K*K);
            int kk = idx % (K*K);
            int gi = i0 + pi / TILE, gj = j0 + pi % TILE;
            s_w[idx] = w[(gi*ROUT + gj)*(K*K) + kk];
        }
        if (tid < TILE*TILE) {
            int gi = i0 + tid / TILE, gj = j0 + tid % TILE;
            s_b[tid] = bias[gi*ROUT + gj];
        }
        __syncthreads();

        // stage input region: LN (+pool) applied on the fly
        for (int idx = tid; idx < S*RT*RT; idx += 256) {
            int ls = idx / (RT*RT);
            int p  = idx % (RT*RT);
            int rr = p / RT, rc = p % RT;
            int ci = i0 - PAD + rr, cj = j0 - PAD + rc;
            float val = 0.0f;
            if (ci >= 0 && ci < CIN && cj >= 0 && cj < CIN) {
                if constexpr (FIRST) {
                    val = in[(S0+ls)*RIN*RIN + ci*RIN + cj];
                } else if constexpr (POOL) {
                    float mu = s_mr[ls], rs = s_mr[S+ls];
                    float best = -3.4e38f;
                    #pragma unroll
                    for (int dy = 0; dy < 2; dy++)
                    #pragma unroll
                    for (int dx = 0; dx < 2; dx++) {
                        int ry = 2*ci+dy, rx = 2*cj+dx;
                        float raw = in[(S0+ls)*RIN*RIN + ry*RIN + rx];
                        float n = (raw-mu)*rs*gamma[ry*RIN+rx] + beta[ry*RIN+rx];
                        best = fmaxf(best, n);
                    }
                    val = best;
                } else {
                    float mu = s_mr[ls], rs = s_mr[S+ls];
                    float raw = in[(S0+ls)*RIN*RIN + ci*RIN + cj];
                    val = (raw-mu)*rs*gamma[ci*RIN+cj] + beta[ci*RIN+cj];
                }
            }
            s_in[ls*PP + p] = val;
        }
        __syncthreads();

        // compute: lane = sample, groups = positions; register row reuse
        const int s   = tid % S;
        const int pg  = tid / S;
        const int p0  = pg * OPT;
        const int ti  = p0 / TILE;
        const int tj0 = p0 % TILE;
        float lsum = 0.f, lsq = 0.f;
        {
            float acc[OPT];
            #pragma unroll
            for (int o = 0; o < OPT; o++) acc[o] = s_b[p0+o];
            #pragma unroll
            for (int ki = 0; ki < K; ki++) {
                float row[OPT+K-1];
                #pragma unroll
                for (int c = 0; c < OPT+K-1; c++)
                    row[c] = s_in[s*PP + (ti+ki)*RT + tj0 + c];
                #pragma unroll
                for (int kj = 0; kj < K; kj++)
                    #pragma unroll
                    for (int o = 0; o < OPT; o++)
                        acc[o] += row[o+kj] * s_w[(p0+o)*(K*K) + ki*K + kj];
            }
            #pragma unroll
            for (int o = 0; o < OPT; o++) {
                float v = fmaxf(acc[o], 0.f);
                out[(S0+s)*ROUT*ROUT + (i0+ti)*ROUT + (j0+tj0+o)] = v;
                lsum += v; lsq += v*v;
            }
        }

        s_red[tid]     = lsum;
        s_red[256+tid] = lsq;
        __syncthreads();
        if (tid < S) {
            float a = 0.f, b = 0.f;
            #pragma unroll
            for (int g = 0; g < PG; g++) { a += s_red[g*S+tid]; b += s_red[256+g*S+tid]; }
            atomicAdd(&stats[S0+tid], a);
            atomicAdd(&stats[64+S0+tid], b);
        }
        __syncthreads();
    }
}

// ---------------------------------------------------------------------------
// FC: LN6 -> flatten(256) -> logits[1024]. Unit = (4-sample group, 256-out
// quarter): each fcw row read once serves 4 samples.
// ---------------------------------------------------------------------------
__device__ void fc_dev(float* sm, const float* __restrict__ t6,
                       const float* __restrict__ stats6,
                       const float* __restrict__ g6, const float* __restrict__ be6,
                       const float* __restrict__ fcw, const float* __restrict__ fcb,
                       float* __restrict__ logits)
{
    float* h = sm;   // 4 x 256
    const int tid = threadIdx.x;
    for (int unit = blockIdx.x; unit < 64; unit += gridDim.x) {
        const int sg = unit >> 2;
        const int q  = unit & 3;
        #pragma unroll
        for (int r = 0; r < 4; r++) {
            int smp = sg*4 + r;
            float mu  = stats6[smp] * (1.f/256.f);
            float msq = stats6[64+smp] * (1.f/256.f);
            float rstd = rsqrtf(msq - mu*mu + LN_EPS);
            h[r*256 + tid] = (t6[smp*256 + tid] - mu)*rstd*g6[tid] + be6[tid];
        }
        __syncthreads();
        const int o = q*256 + tid;
        const float4* wr = (const float4*)(fcw + o*256);
        const float4* h4 = (const float4*)h;
        float a0=0.f, a1=0.f, a2=0.f, a3=0.f;
        #pragma unroll 4
        for (int k = 0; k < 64; k++) {
            float4 wv = wr[k];
            float4 h0 = h4[k], h1 = h4[64+k], h2 = h4[128+k], h3 = h4[192+k];
            a0 += wv.x*h0.x + wv.y*h0.y + wv.z*h0.z + wv.w*h0.w;
            a1 += wv.x*h1.x + wv.y*h1.y + wv.z*h1.z + wv.w*h1.w;
            a2 += wv.x*h2.x + wv.y*h2.y + wv.z*h2.z + wv.w*h2.w;
            a3 += wv.x*h3.x + wv.y*h3.y + wv.z*h3.z + wv.w*h3.w;
        }
        float bo = fcb[o];
        logits[(sg*4+0)*1024 + o] = a0 + bo;
        logits[(sg*4+1)*1024 + o] = a1 + bo;
        logits[(sg*4+2)*1024 + o] = a2 + bo;
        logits[(sg*4+3)*1024 + o] = a3 + bo;
        __syncthreads();
    }
}

// ---------------------------------------------------------------------------
__device__ void softmax_dev(float* sm, const float* __restrict__ logits,
                            float* __restrict__ outp)
{
    float* red = sm;
    const int tid = threadIdx.x;
    for (int unit = blockIdx.x; unit < 64; unit += gridDim.x) {
        float4 v = ((const float4*)(logits + unit*1024))[tid];
        float lmax = fmaxf(fmaxf(v.x,v.y), fmaxf(v.z,v.w));
        red[tid] = lmax;
        __syncthreads();
        for (int off=128; off>0; off>>=1) {
            if (tid<off) red[tid]=fmaxf(red[tid],red[tid+off]);
            __syncthreads();
        }
        float M = red[0];
        __syncthreads();
        float4 e;
        e.x=expf(v.x-M); e.y=expf(v.y-M); e.z=expf(v.z-M); e.w=expf(v.w-M);
        red[tid] = e.x+e.y+e.z+e.w;
        __syncthreads();
        for (int off=128; off>0; off>>=1) {
            if (tid<off) red[tid]+=red[tid+off];
            __syncthreads();
        }
        float inv = 1.0f/red[0];
        e.x*=inv; e.y*=inv; e.z*=inv; e.w*=inv;
        ((float4*)(outp + unit*1024))[tid] = e;
        __syncthreads();
    }
}

// ---------------------------------------------------------------------------
__global__ __launch_bounds__(256, 2) void allnet(Params p)
{
    __shared__ __align__(16) float sm[SMEM_FLOATS];
    cg::grid_group grid = cg::this_grid();

    float* t1 = p.ws;                  // 64*128*128 (later reused for logits)
    float* t2 = t1 + 64*128*128;
    float* t3 = t2 + 64*64*64;
    float* t4 = t3 + 64*64*64;
    float* t5 = t4 + 64*32*32;
    float* t6 = t5 + 64*32*32;
    float* st = t6 + 64*16*16;

    // S1: x[128] --7x7--> t1[128]            (256 tiles x 2 sgroups = 512 units)
    lc_stage_dev<128,false,true, 7,8,32>(sm, p.x, nullptr, nullptr, nullptr, p.w1, p.b1, t1, st);
    grid.sync();
    // S2: LN1+pool -> 64 --5x5--> t2         (64 tiles x 8 = 512 units)
    lc_stage_dev<128,true, false,5,8,8 >(sm, t1, st,     p.g1, p.be1, p.w2, p.b2, t2, st+128);
    grid.sync();
    // S3: LN2 --5x5--> t3[64]                (512 units)
    lc_stage_dev<64, false,false,5,8,8 >(sm, t2, st+128, p.g2, p.be2, p.w3, p.b3, t3, st+256);
    grid.sync();
    // S4: LN3+pool -> 32 --3x3--> t4         (64 tiles x 4 = 256 units)
    lc_stage_dev<64, true, false,3,4,16>(sm, t3, st+256, p.g3, p.be3, p.w4, p.b4, t4, st+384);
    grid.sync();
    // S5: LN4 --3x3--> t5[32]                (256 units)
    lc_stage_dev<32, false,false,3,4,16>(sm, t4, st+384, p.g4, p.be4, p.w5, p.b5, t5, st+512);
    grid.sync();
    // S6: LN5+pool -> 16 --3x3--> t6         (16 tiles x 4 = 64 units)
    lc_stage_dev<32, true, false,3,4,16>(sm, t5, st+512, p.g5, p.be5, p.w6, p.b6, t6, st+640);
    grid.sync();
    fc_dev(sm, t6, st+640, p.g6, p.be6, p.fcw, p.fcb, t1);
    grid.sync();
    softmax_dev(sm, t1, p.out);
}

// ---------------------------------------------------------------------------
extern "C" void kernel_launch(void* const* d_in, const int* in_sizes, int n_in,
                              void* d_out, int out_size, void* d_ws, size_t ws_size,
                              hipStream_t stream) {
    (void)in_sizes; (void)n_in; (void)out_size; (void)ws_size;

    Params p;
    p.x   = (const float*)d_in[0];
    p.w1  = (const float*)d_in[1];  p.b1  = (const float*)d_in[2];
    p.g1  = (const float*)d_in[3];  p.be1 = (const float*)d_in[4];
    p.w2  = (const float*)d_in[5];  p.b2  = (const float*)d_in[6];
    p.g2  = (const float*)d_in[7];  p.be2 = (const float*)d_in[8];
    p.w3  = (const float*)d_in[9];  p.b3  = (const float*)d_in[10];
    p.g3  = (const float*)d_in[11]; p.be3 = (const float*)d_in[12];
    p.w4  = (const float*)d_in[13]; p.b4  = (const float*)d_in[14];
    p.g4  = (const float*)d_in[15]; p.be4 = (const float*)d_in[16];
    p.w5  = (const float*)d_in[17]; p.b5  = (const float*)d_in[18];
    p.g5  = (const float*)d_in[19]; p.be5 = (const float*)d_in[20];
    p.w6  = (const float*)d_in[21]; p.b6  = (const float*)d_in[22];
    p.g6  = (const float*)d_in[23]; p.be6 = (const float*)d_in[24];
    p.fcw = (const float*)d_in[25]; p.fcb = (const float*)d_in[26];
    p.out = (float*)d_out;
    p.ws  = (float*)d_ws;

    // zero the 6 stages' LN stats (6 x [sum(64), sumsq(64)])
    float* st = p.ws + 64*128*128 + 2*(64*64*64) + 2*(64*32*32) + 64*16*16;
    hipMemsetAsync(st, 0, 6 * 128 * sizeof(float), stream);

    void* args[] = { (void*)&p };
    hipLaunchCooperativeKernel((void*)allnet, dim3(GRID_BLOCKS), dim3(256),
                               args, 0, stream);
}

// Round 4
// 200.109 us; speedup vs baseline: 2.9613x; 2.9613x over previous
//
#include <hip/hip_runtime.h>

#define LN_EPS 1e-5f

// ---------------------------------------------------------------------------
// K1: stage-1 locally-connected conv 7x7 pad 3, 128x128 -> raw ReLU out (t1).
// Block = 8x8 tile x 16 samples. Grid = 256 tiles x 4 sample-groups = 1024.
// No stats here: K2 computes LN1 stats per sample in-block.
// ---------------------------------------------------------------------------
__global__ __launch_bounds__(256) void s1_conv(const float* __restrict__ x,
                                               const float* __restrict__ w,
                                               const float* __restrict__ bias,
                                               float* __restrict__ out)
{
    constexpr int R = 128, K = 7, TILE = 8, S = 16, PAD = 3;
    constexpr int RT = TILE + K - 1;          // 14
    constexpr int PP = RT * RT + 1;           // 197 (odd -> conflict-light)
    constexpr int NBLK = R / TILE;            // 16
    constexpr int WCNT = TILE * TILE * K * K; // 3136
    constexpr int PG = 256 / S;               // 16
    constexpr int OPT = TILE * TILE / PG;     // 4

    __shared__ float s_in[S * PP];
    __shared__ float s_w[WCNT];
    __shared__ float s_b[TILE * TILE];

    const int tid = threadIdx.x;
    const int bt = blockIdx.x % (NBLK * NBLK);
    const int sg = blockIdx.x / (NBLK * NBLK);
    const int i0 = (bt / NBLK) * TILE;
    const int j0 = (bt % NBLK) * TILE;
    const int S0 = sg * S;

    for (int idx = tid; idx < WCNT; idx += 256) {
        int pi = idx / (K * K), kk = idx % (K * K);
        int gi = i0 + pi / TILE, gj = j0 + pi % TILE;
        s_w[idx] = w[(gi * R + gj) * (K * K) + kk];
    }
    if (tid < TILE * TILE)
        s_b[tid] = bias[(i0 + tid / TILE) * R + (j0 + tid % TILE)];

    for (int idx = tid; idx < S * RT * RT; idx += 256) {
        int ls = idx / (RT * RT), p = idx % (RT * RT);
        int ci = i0 - PAD + p / RT, cj = j0 - PAD + p % RT;
        float v = 0.0f;
        if (ci >= 0 && ci < R && cj >= 0 && cj < R)
            v = x[(S0 + ls) * R * R + ci * R + cj];
        s_in[ls * PP + p] = v;
    }
    __syncthreads();

    const int s = tid % S;
    const int pg = tid / S;
    const int p0 = pg * OPT;
    const int ti = p0 / TILE, tj0 = p0 % TILE;
    float acc[OPT];
    #pragma unroll
    for (int o = 0; o < OPT; o++) acc[o] = s_b[p0 + o];
    #pragma unroll
    for (int ki = 0; ki < K; ki++) {
        float row[OPT + K - 1];
        #pragma unroll
        for (int c = 0; c < OPT + K - 1; c++)
            row[c] = s_in[s * PP + (ti + ki) * RT + tj0 + c];
        #pragma unroll
        for (int kj = 0; kj < K; kj++)
            #pragma unroll
            for (int o = 0; o < OPT; o++)
                acc[o] += row[o + kj] * s_w[(p0 + o) * (K * K) + ki * K + kj];
    }
    #pragma unroll
    for (int o = 0; o < OPT; o++)
        out[(S0 + s) * R * R + (i0 + ti) * R + (j0 + tj0 + o)] = fmaxf(acc[o], 0.0f);
}

// ---------------------------------------------------------------------------
// K2 helpers (one block = one sample; 256 threads)
// ---------------------------------------------------------------------------
__device__ __forceinline__ void stats_reduce(float* red, float lsum, float lsq,
                                             float inv_n, float* s_mu, float* s_rs)
{
    const int tid = threadIdx.x;
    #pragma unroll
    for (int off = 32; off > 0; off >>= 1) {
        lsum += __shfl_down(lsum, off, 64);
        lsq  += __shfl_down(lsq,  off, 64);
    }
    if ((tid & 63) == 0) { red[tid >> 6] = lsum; red[8 + (tid >> 6)] = lsq; }
    __syncthreads();
    if (tid == 0) {
        float a = red[0] + red[1] + red[2] + red[3];
        float b = red[8] + red[9] + red[10] + red[11];
        float mu = a * inv_n, ms = b * inv_n;
        *s_mu = mu;
        *s_rs = rsqrtf(ms - mu * mu + LN_EPS);
    }
    __syncthreads();
}

// conv KxK pad (K-1)/2 over M x M LDS map (stride M+1) -> ReLU into R (stride M+1),
// accumulating sum/sumsq of the ReLU'd outputs. Weights streamed from global.
template<int M, int K>
__device__ __forceinline__ void conv_lds(const float* __restrict__ I,
                                         const float* __restrict__ w,
                                         const float* __restrict__ bias,
                                         float* __restrict__ R,
                                         float& lsum, float& lsq)
{
    constexpr int OPT = (M * M) / 256;
    constexpr int PADK = (K - 1) / 2;
    constexpr int STR = M + 1;
    const int tid = threadIdx.x;
    const int p0 = tid * OPT;
    const int i = p0 / M, j0 = p0 % M;
    const float* wb = w + p0 * K * K;

    float acc[OPT];
    #pragma unroll
    for (int o = 0; o < OPT; o++) acc[o] = bias[p0 + o];
    #pragma unroll
    for (int ki = 0; ki < K; ki++) {
        int ii = i - PADK + ki;
        float row[OPT + K - 1];
        if (ii >= 0 && ii < M) {
            #pragma unroll
            for (int c = 0; c < OPT + K - 1; c++) {
                int jj = j0 - PADK + c;
                row[c] = (jj >= 0 && jj < M) ? I[ii * STR + jj] : 0.0f;
            }
        } else {
            #pragma unroll
            for (int c = 0; c < OPT + K - 1; c++) row[c] = 0.0f;
        }
        #pragma unroll
        for (int kj = 0; kj < K; kj++)
            #pragma unroll
            for (int o = 0; o < OPT; o++)
                acc[o] += row[o + kj] * wb[o * K * K + ki * K + kj];
    }
    #pragma unroll
    for (int o = 0; o < OPT; o++) {
        float v = fmaxf(acc[o], 0.0f);
        R[i * STR + j0 + o] = v;
        lsum += v;
        lsq  += v * v;
    }
}

// LN (+ optional 2x2 maxpool) of raw map R (res N, stride N+1) -> I
// (res M = N or N/2, stride M+1). gamma/beta indexed at input res N.
template<int N, bool POOL>
__device__ __forceinline__ void transform(const float* __restrict__ R,
                                          float mu, float rs,
                                          const float* __restrict__ g,
                                          const float* __restrict__ b,
                                          float* __restrict__ I)
{
    constexpr int M = POOL ? N / 2 : N;
    constexpr int SR = N + 1, SI = M + 1;
    const int tid = threadIdx.x;
    for (int p = tid; p < M * M; p += 256) {
        int i = p / M, j = p % M;
        float v;
        if constexpr (POOL) {
            float best = -3.4e38f;
            #pragma unroll
            for (int dy = 0; dy < 2; dy++)
                #pragma unroll
                for (int dx = 0; dx < 2; dx++) {
                    int r = 2 * i + dy, c = 2 * j + dx;
                    float n = (R[r * SR + c] - mu) * rs * g[r * N + c] + b[r * N + c];
                    best = fmaxf(best, n);
                }
            v = best;
        } else {
            v = (R[i * SR + j] - mu) * rs * g[i * N + j] + b[i * N + j];
        }
        I[i * SI + j] = v;
    }
}

// ---------------------------------------------------------------------------
// K2: everything after stage-1 conv, one block per sample.
// ---------------------------------------------------------------------------
__global__ __launch_bounds__(256) void tail_fused(
    const float* __restrict__ t1,
    const float* __restrict__ g1, const float* __restrict__ be1,
    const float* __restrict__ w2, const float* __restrict__ b2,
    const float* __restrict__ g2, const float* __restrict__ be2,
    const float* __restrict__ w3, const float* __restrict__ b3,
    const float* __restrict__ g3, const float* __restrict__ be3,
    const float* __restrict__ w4, const float* __restrict__ b4,
    const float* __restrict__ g4, const float* __restrict__ be4,
    const float* __restrict__ w5, const float* __restrict__ b5,
    const float* __restrict__ g5, const float* __restrict__ be5,
    const float* __restrict__ w6, const float* __restrict__ b6,
    const float* __restrict__ g6, const float* __restrict__ be6,
    const float* __restrict__ fcw, const float* __restrict__ fcb,
    float* __restrict__ outp)
{
    __shared__ __align__(16) float I[64 * 65];
    __shared__ __align__(16) float R[64 * 65];
    __shared__ __align__(16) float h[256];
    __shared__ float red[16];
    __shared__ float s_mu, s_rs;

    const int s = blockIdx.x;
    const int tid = threadIdx.x;
    const float* x1 = t1 + s * 16384;

    // LN1 stats over raw stage-1 output (global, float4)
    float ls = 0.f, lq = 0.f;
    const float4* x4 = (const float4*)x1;
    for (int i = tid; i < 4096; i += 256) {
        float4 v = x4[i];
        ls += v.x + v.y + v.z + v.w;
        lq += v.x * v.x + v.y * v.y + v.z * v.z + v.w * v.w;
    }
    stats_reduce(red, ls, lq, 1.f / 16384.f, &s_mu, &s_rs);

    // pool(LN1(t1)) -> I (64x64, stride 65)
    {
        float mu = s_mu, rs = s_rs;
        for (int p = tid; p < 4096; p += 256) {
            int i = p >> 6, j = p & 63;
            float best = -3.4e38f;
            #pragma unroll
            for (int dy = 0; dy < 2; dy++)
                #pragma unroll
                for (int dx = 0; dx < 2; dx++) {
                    int r = 2 * i + dy, c = 2 * j + dx;
                    float n = (x1[r * 128 + c] - mu) * rs * g1[r * 128 + c] + be1[r * 128 + c];
                    best = fmaxf(best, n);
                }
            I[i * 65 + j] = best;
        }
    }
    __syncthreads();

    // S2: conv5 -> R, LN2 stats
    ls = lq = 0.f; conv_lds<64, 5>(I, w2, b2, R, ls, lq);
    stats_reduce(red, ls, lq, 1.f / 4096.f, &s_mu, &s_rs);
    transform<64, false>(R, s_mu, s_rs, g2, be2, I);
    __syncthreads();

    // S3: conv5 -> R, LN3 stats, pool -> 32
    ls = lq = 0.f; conv_lds<64, 5>(I, w3, b3, R, ls, lq);
    stats_reduce(red, ls, lq, 1.f / 4096.f, &s_mu, &s_rs);
    transform<64, true>(R, s_mu, s_rs, g3, be3, I);
    __syncthreads();

    // S4: conv3 (32) -> R, LN4
    ls = lq = 0.f; conv_lds<32, 3>(I, w4, b4, R, ls, lq);
    stats_reduce(red, ls, lq, 1.f / 1024.f, &s_mu, &s_rs);
    transform<32, false>(R, s_mu, s_rs, g4, be4, I);
    __syncthreads();

    // S5: conv3 (32) -> R, LN5, pool -> 16
    ls = lq = 0.f; conv_lds<32, 3>(I, w5, b5, R, ls, lq);
    stats_reduce(red, ls, lq, 1.f / 1024.f, &s_mu, &s_rs);
    transform<32, true>(R, s_mu, s_rs, g5, be5, I);
    __syncthreads();

    // S6: conv3 (16) -> R, LN6
    ls = lq = 0.f; conv_lds<16, 3>(I, w6, b6, R, ls, lq);
    stats_reduce(red, ls, lq, 1.f / 256.f, &s_mu, &s_rs);

    // LN6 -> h[256]
    {
        int i = tid >> 4, j = tid & 15;
        h[tid] = (R[i * 17 + j] - s_mu) * s_rs * g6[tid] + be6[tid];
    }
    __syncthreads();

    // FC 256->1024 (4 rows per thread) + softmax (in registers + shuffles)
    const float4* h4 = (const float4*)h;
    float la[4];
    float lmax = -3.4e38f;
    #pragma unroll
    for (int r = 0; r < 4; r++) {
        int o = r * 256 + tid;
        const float4* wr = (const float4*)(fcw + o * 256);
        float acc = 0.f;
        #pragma unroll 8
        for (int k = 0; k < 64; k++) {
            float4 wv = wr[k];
            float4 hv = h4[k];
            acc += wv.x * hv.x + wv.y * hv.y + wv.z * hv.z + wv.w * hv.w;
        }
        acc += fcb[o];
        la[r] = acc;
        lmax = fmaxf(lmax, acc);
    }
    #pragma unroll
    for (int off = 32; off > 0; off >>= 1)
        lmax = fmaxf(lmax, __shfl_down(lmax, off, 64));
    if ((tid & 63) == 0) red[tid >> 6] = lmax;
    __syncthreads();
    if (tid == 0)
        s_mu = fmaxf(fmaxf(red[0], red[1]), fmaxf(red[2], red[3]));
    __syncthreads();
    float M = s_mu;

    float e[4];
    float lsum = 0.f;
    #pragma unroll
    for (int r = 0; r < 4; r++) { e[r] = expf(la[r] - M); lsum += e[r]; }
    #pragma unroll
    for (int off = 32; off > 0; off >>= 1)
        lsum += __shfl_down(lsum, off, 64);
    if ((tid & 63) == 0) red[8 + (tid >> 6)] = lsum;
    __syncthreads();
    if (tid == 0)
        s_rs = 1.0f / (red[8] + red[9] + red[10] + red[11]);
    __syncthreads();
    float inv = s_rs;
    #pragma unroll
    for (int r = 0; r < 4; r++)
        outp[s * 1024 + r * 256 + tid] = e[r] * inv;
}

// ---------------------------------------------------------------------------
extern "C" void kernel_launch(void* const* d_in, const int* in_sizes, int n_in,
                              void* d_out, int out_size, void* d_ws, size_t ws_size,
                              hipStream_t stream) {
    (void)in_sizes; (void)n_in; (void)out_size; (void)ws_size;

    const float* x   = (const float*)d_in[0];
    const float* w1  = (const float*)d_in[1];  const float* b1  = (const float*)d_in[2];
    const float* g1  = (const float*)d_in[3];  const float* be1 = (const float*)d_in[4];
    const float* w2  = (const float*)d_in[5];  const float* b2  = (const float*)d_in[6];
    const float* g2  = (const float*)d_in[7];  const float* be2 = (const float*)d_in[8];
    const float* w3  = (const float*)d_in[9];  const float* b3  = (const float*)d_in[10];
    const float* g3  = (const float*)d_in[11]; const float* be3 = (const float*)d_in[12];
    const float* w4  = (const float*)d_in[13]; const float* b4  = (const float*)d_in[14];
    const float* g4  = (const float*)d_in[15]; const float* be4 = (const float*)d_in[16];
    const float* w5  = (const float*)d_in[17]; const float* b5  = (const float*)d_in[18];
    const float* g5  = (const float*)d_in[19]; const float* be5 = (const float*)d_in[20];
    const float* w6  = (const float*)d_in[21]; const float* b6  = (const float*)d_in[22];
    const float* g6  = (const float*)d_in[23]; const float* be6 = (const float*)d_in[24];
    const float* fcw = (const float*)d_in[25]; const float* fcb = (const float*)d_in[26];

    float* t1 = (float*)d_ws;   // 64*128*128 floats

    s1_conv<<<1024, 256, 0, stream>>>(x, w1, b1, t1);
    tail_fused<<<64, 256, 0, stream>>>(t1,
        g1, be1, w2, b2, g2, be2, w3, b3, g3, be3,
        w4, b4, g4, be4, w5, b5, g5, be5, w6, b6, g6, be6,
        fcw, fcb, (float*)d_out);
}